// Round 6
// baseline (1026.957 us; speedup 1.0000x reference)
//
#include <hip/hip_runtime.h>

// Mamba selective scan: BATCH=2, DIM=768, L=2048, N=16, fp32.
// R6: ONE kernel, 3 phases separated by a software grid barrier
// (device-scope atomics; counters zeroed by hipMemsetAsync each launch).
// 768 blocks x 256 thr, 41.6 KB LDS => exactly 3 blocks/CU (LDS-bound),
// so all blocks are co-resident; __launch_bounds__(256,3) caps VGPR at 168.
//  A: stage delta/u [64d][64l] + B/C [16n][64l] coalesced; per-wave chunk
//     scan (LC=16); h ([b][c][n][d]) + S stored coalesced. sp/uu/A2/x in regs.
//  B: cross-chunk serial combine (first 24576 threads), h -> x_init in place.
//  C: rescan with inits (sp/uu persist in registers!), y via LDS slab,
//     coalesced fused epilogue.

#define LOG2E 1.4426950408889634f
#define LN2   0.6931471805599453f

constexpr int BATCH = 2, DIM = 768, L = 2048, N = 16;
constexpr int NC = 128, LC = 16;       // chunks, steps per chunk
constexpr int DG = DIM / 64;           // 12 d-groups
constexpr int CPB = 4;                 // chunks per block (1 per wave)
constexpr int CG = NC / CPB;           // 32 chunk-groups
constexpr int NBLK = BATCH * DG * CG;  // 768 blocks = exactly 3/CU
constexpr int NCOMB = BATCH * DIM * N; // 24576 combine threads
static_assert(NC * LC == L, "chunking must cover L");

__device__ __forceinline__ float fexp2(float x) { return __builtin_amdgcn_exp2f(x); }
__device__ __forceinline__ float softplus(float v) {
  float s = LN2 * __log2f(1.0f + fexp2(v * LOG2E));
  return (v > 20.0f) ? v : s;
}
__device__ __forceinline__ float silu(float v) { return v / (1.0f + fexp2(-v * LOG2E)); }

// software grid barrier: counter id zeroed before launch; each block arrives
// once. Device-scope fence both sides (XCD L2s are not cross-coherent).
__device__ __forceinline__ void gridbar(unsigned* bar, int id, int t) {
  __syncthreads();
  if (t == 0) {
    __threadfence();   // release: make this block's global writes visible
    __hip_atomic_fetch_add(&bar[id * 32], 1u, __ATOMIC_ACQ_REL, __HIP_MEMORY_SCOPE_AGENT);
    while (__hip_atomic_load(&bar[id * 32], __ATOMIC_ACQUIRE, __HIP_MEMORY_SCOPE_AGENT)
           < (unsigned)NBLK) {
      __builtin_amdgcn_s_sleep(8);
    }
  }
  __syncthreads();
  __threadfence();     // acquire: invalidate stale cached lines before reads
}

__global__ __launch_bounds__(256, 3) void k_one(
    const float* __restrict__ u, const float* __restrict__ delta,
    const float* __restrict__ A, const float* __restrict__ dbias,
    const float* __restrict__ Bg, const float* __restrict__ Cg,
    const float* __restrict__ Dv, const float* __restrict__ z,
    float* __restrict__ h, float* __restrict__ S, unsigned* __restrict__ bar,
    float* __restrict__ out)
{
  __shared__ float ds_[64][65];   // delta slab; reused as y slab in phase C
  __shared__ float us[64][65];
  __shared__ float Bs[N][65];
  __shared__ float Cs[N][65];

  const int bid = blockIdx.x, t = threadIdx.x;
  const int cgi = bid & 31;
  const int dgb = bid >> 5;
  const int dg = dgb % DG;
  const int b = dgb / DG;
  const int d0 = dg * 64, l0 = cgi * 64;

  {  // coalesced staging
    const int row16 = t >> 4;
    const int col4 = (t & 15) * 4;
#pragma unroll
    for (int rr = 0; rr < 4; rr++) {
      int row = row16 + rr * 16;
      long gof = ((long)(b * DIM + d0 + row)) * L + l0 + col4;
      *(float4*)&ds_[row][col4] = *(const float4*)(delta + gof);
      *(float4*)&us[row][col4]  = *(const float4*)(u + gof);
    }
    long bof = ((long)(b * N + row16)) * L + l0 + col4;
    *(float4*)&Bs[row16][col4] = *(const float4*)(Bg + bof);
    *(float4*)&Cs[row16][col4] = *(const float4*)(Cg + bof);
  }

  const int w = t >> 6, lane = t & 63;
  const int c = cgi * CPB + w;
  const int d = d0 + lane;

  float A2[N];
#pragma unroll
  for (int q = 0; q < 4; q++) {
    float4 av = *(const float4*)(A + d * N + q * 4);
    A2[q*4+0] = av.x * LOG2E; A2[q*4+1] = av.y * LOG2E;
    A2[q*4+2] = av.z * LOG2E; A2[q*4+3] = av.w * LOG2E;
  }
  const float bias = dbias[d];

  __syncthreads();

  // ---- phase A: softplus once, chunk-local scan from zero ----
  float sp[LC], uu[LC], Ssum = 0.f;
#pragma unroll
  for (int j = 0; j < LC; j++) {
    float dv = ds_[lane][w * LC + j];
    uu[j] = us[lane][w * LC + j];
    sp[j] = softplus(dv + bias);
    Ssum += sp[j];
  }

  float x[N];
#pragma unroll
  for (int n = 0; n < N; n++) x[n] = 0.f;
#pragma unroll
  for (int j = 0; j < LC; j++) {
    float du = sp[j] * uu[j];
#pragma unroll
    for (int n = 0; n < N; n++) {
      float a = fexp2(sp[j] * A2[n]);
      x[n] = a * x[n] + du * Bs[n][w * LC + j];
    }
  }

  const long hb = ((long)(b * NC + c)) * N * DIM + d;   // [b][c][n][d]
#pragma unroll
  for (int n = 0; n < N; n++) h[hb + (long)n * DIM] = x[n];
  S[(b * NC + c) * DIM + d] = Ssum;

  gridbar(bar, 0, t);

  // ---- phase B: serial combine over chunks (first NCOMB threads) ----
  {
    int g = bid * 256 + t;                 // d-fastest map: g=(bb*16+n)*768+dd
    if (g < NCOMB) {
      int dd = g % DIM;
      int r = g / DIM;
      int n = r & 15;
      int bb = r >> 4;
      float a2 = A[dd * N + n] * LOG2E;
      float xx = 0.f;
#pragma unroll 8
      for (int cc = 0; cc < NC; cc++) {
        long idx = (((long)(bb * NC + cc)) * N + n) * DIM + dd;
        float hc = h[idx];
        float Sc = S[(bb * NC + cc) * DIM + dd];
        h[idx] = xx;                       // x_init for chunk cc
        xx = fexp2(Sc * a2) * xx + hc;
      }
    }
  }

  gridbar(bar, 1, t);

  // ---- phase C: rescan with inits (sp/uu/A2 still in registers) ----
#pragma unroll
  for (int n = 0; n < N; n++) x[n] = h[hb + (long)n * DIM];

  float y[LC];
#pragma unroll
  for (int j = 0; j < LC; j++) {
    float du = sp[j] * uu[j];
    float acc = 0.f;
#pragma unroll
    for (int n = 0; n < N; n++) {
      float a = fexp2(sp[j] * A2[n]);
      x[n] = a * x[n] + du * Bs[n][w * LC + j];
      acc += x[n] * Cs[n][w * LC + j];
    }
    y[j] = acc;
  }
  __syncthreads();   // everyone done with ds_-as-delta (consumed in phase A)
#pragma unroll
  for (int j = 0; j < LC; j++) ds_[lane][w * LC + j] = y[j];

  __syncthreads();

  // coalesced fused epilogue: out = (y + u*D) * silu(z)
  {
    const int row16 = t >> 4;
    const int col4 = (t & 15) * 4;
#pragma unroll
    for (int rr = 0; rr < 4; rr++) {
      int row = row16 + rr * 16;
      long gof = ((long)(b * DIM + d0 + row)) * L + l0 + col4;
      float4 zv = *(const float4*)(z + gof);
      float4 yv = *(const float4*)&ds_[row][col4];
      float4 uv = *(const float4*)&us[row][col4];
      float Dd = Dv[d0 + row];
      float4 ov;
      ov.x = (yv.x + uv.x * Dd) * silu(zv.x);
      ov.y = (yv.y + uv.y * Dd) * silu(zv.y);
      ov.z = (yv.z + uv.z * Dd) * silu(zv.z);
      ov.w = (yv.w + uv.w * Dd) * silu(zv.w);
      *(float4*)(out + gof) = ov;
    }
  }
}

// ---------------- fallback (ws too small) ----------------
__global__ __launch_bounds__(256) void k_simple(
    const float* __restrict__ u, const float* __restrict__ delta,
    const float* __restrict__ A, const float* __restrict__ dbias,
    const float* __restrict__ Bm, const float* __restrict__ Cm,
    const float* __restrict__ Dv, const float* __restrict__ z,
    float* __restrict__ out) {
  int t = blockIdx.x * 256 + threadIdx.x;
  int n = t % N;
  int bd = t / N;
  int d = bd % DIM;
  int b = bd / DIM;
  float A2 = A[d * N + n] * LOG2E;
  float bias = dbias[d];
  float Dd = Dv[d];
  const float* Bp = Bm + ((long)b * N + n) * L;
  const float* Cp = Cm + ((long)b * N + n) * L;
  long base = (long)bd * L;
  float x = 0.0f;
  for (int l = 0; l < L; l++) {
    float dv = delta[base + l];
    float uv = u[base + l];
    float sp = softplus(dv + bias);
    float a = fexp2(sp * A2);
    x = a * x + sp * uv * Bp[l];
    float y = x * Cp[l];
#pragma unroll
    for (int off = 8; off; off >>= 1) y += __shfl_xor(y, off, 16);
    if (n == 0) {
      float zv = z[base + l];
      out[base + l] = (y + uv * Dd) * silu(zv);
    }
  }
}

extern "C" void kernel_launch(void* const* d_in, const int* in_sizes, int n_in,
                              void* d_out, int out_size, void* d_ws, size_t ws_size,
                              hipStream_t stream) {
  const float* u     = (const float*)d_in[0];
  const float* delta = (const float*)d_in[1];
  const float* A     = (const float*)d_in[2];
  const float* Bm    = (const float*)d_in[3];
  const float* Cm    = (const float*)d_in[4];
  const float* Dv    = (const float*)d_in[5];
  const float* z     = (const float*)d_in[6];
  const float* dbias = (const float*)d_in[7];
  float* out = (float*)d_out;

  const size_t hp  = (size_t)BATCH * NC * DIM * N;  // 3.15M floats
  const size_t spn = (size_t)BATCH * NC * DIM;      // 196K floats
  const size_t need = (hp + spn) * sizeof(float) + 256;

  if (ws_size < need) {
    k_simple<<<(BATCH * DIM * N) / 256, 256, 0, stream>>>(u, delta, A, dbias, Bm, Cm, Dv, z, out);
    return;
  }

  float* h = (float*)d_ws;
  float* S = h + hp;
  unsigned* bar = (unsigned*)(S + spn);   // 2 counters, 128B apart

  hipMemsetAsync(bar, 0, 256, stream);    // re-zero barrier counters (graph-safe)
  k_one<<<NBLK, 256, 0, stream>>>(u, delta, A, dbias, Bm, Cm, Dv, z, h, S, bar, out);
}

// Round 7
// 130.599 us; speedup vs baseline: 7.8634x; 7.8634x over previous
//
#include <hip/hip_runtime.h>

// Mamba selective scan: BATCH=2, DIM=768, L=2048, N=16, fp32.
// R7: 3 plain kernels (R5 structure). New vs R5:
//  - B/C staged TRANSPOSED in LDS (l-major, [64][20]) so the scan reads a
//    16-float row via 4 broadcast ds_read_b128 instead of 16 ds_read_b32.
//  - delta/u slabs padded to 68 (16B-aligned rows) -> float4 LDS pulls.
//  - y slab written via float4.
// Grid-barrier fusion abandoned: R6 showed agent-scope spin + threadfence
// costs 100s of µs on gfx950 (L2 wb/inv + cross-XCD line ping-pong).

#define LOG2E 1.4426950408889634f
#define LN2   0.6931471805599453f

constexpr int BATCH = 2, DIM = 768, L = 2048, N = 16;
constexpr int NC = 128, LC = 16;       // chunks, steps per chunk
constexpr int DG = DIM / 64;           // 12 d-groups
constexpr int CPB = 4;                 // chunks per block (1 per wave)
constexpr int CG = NC / CPB;           // 32 chunk-groups
constexpr int NBLK = BATCH * DG * CG;  // 768 blocks
constexpr int NCOMB = BATCH * DIM * N; // 24576 combine threads
static_assert(NC * LC == L, "chunking must cover L");

__device__ __forceinline__ float fexp2(float x) { return __builtin_amdgcn_exp2f(x); }
__device__ __forceinline__ float softplus(float v) {
  float s = LN2 * __log2f(1.0f + fexp2(v * LOG2E));
  return (v > 20.0f) ? v : s;
}
__device__ __forceinline__ float silu(float v) { return v / (1.0f + fexp2(-v * LOG2E)); }

// ---------------- pass 1 ----------------
__global__ __launch_bounds__(256, 4) void k_pass1(
    const float* __restrict__ u, const float* __restrict__ delta,
    const float* __restrict__ A, const float* __restrict__ dbias,
    const float* __restrict__ Bg, float* __restrict__ h, float* __restrict__ S)
{
  __shared__ float ds_[64][68];   // [d][l], rows 16B-aligned
  __shared__ float us[64][68];
  __shared__ float Bsr[64][20];   // [l][n] transposed, rows 16B-aligned

  const int bid = blockIdx.x, t = threadIdx.x;
  const int cgi = bid & 31;
  const int dgb = bid >> 5;
  const int dg = dgb % DG;
  const int b = dgb / DG;
  const int d0 = dg * 64, l0 = cgi * 64;

  {  // coalesced staging
    const int row16 = t >> 4;          // 0..15
    const int col4 = (t & 15) * 4;     // 0..60
#pragma unroll
    for (int rr = 0; rr < 4; rr++) {
      int row = row16 + rr * 16;
      long gof = ((long)(b * DIM + d0 + row)) * L + l0 + col4;
      *(float4*)&ds_[row][col4] = *(const float4*)(delta + gof);
      *(float4*)&us[row][col4]  = *(const float4*)(u + gof);
    }
    // B: read (n=row16, l=col4..col4+3) coalesced, write transposed
    long bof = ((long)(b * N + row16)) * L + l0 + col4;
    float4 v = *(const float4*)(Bg + bof);
    Bsr[col4 + 0][row16] = v.x;
    Bsr[col4 + 1][row16] = v.y;
    Bsr[col4 + 2][row16] = v.z;
    Bsr[col4 + 3][row16] = v.w;
  }

  const int w = t >> 6, lane = t & 63;
  const int c = cgi * CPB + w;
  const int d = d0 + lane;

  float A2[N];
#pragma unroll
  for (int q = 0; q < 4; q++) {
    float4 av = *(const float4*)(A + d * N + q * 4);
    A2[q*4+0] = av.x * LOG2E; A2[q*4+1] = av.y * LOG2E;
    A2[q*4+2] = av.z * LOG2E; A2[q*4+3] = av.w * LOG2E;
  }
  const float bias = dbias[d];

  __syncthreads();

  float sp[LC], uu[LC], Ssum = 0.f;
#pragma unroll
  for (int q = 0; q < 4; q++) {
    float4 dv = *(const float4*)&ds_[lane][w * LC + q * 4];
    float4 uv = *(const float4*)&us[lane][w * LC + q * 4];
    sp[q*4+0] = softplus(dv.x + bias); uu[q*4+0] = uv.x;
    sp[q*4+1] = softplus(dv.y + bias); uu[q*4+1] = uv.y;
    sp[q*4+2] = softplus(dv.z + bias); uu[q*4+2] = uv.z;
    sp[q*4+3] = softplus(dv.w + bias); uu[q*4+3] = uv.w;
  }
#pragma unroll
  for (int j = 0; j < LC; j++) Ssum += sp[j];

  float x[N];
#pragma unroll
  for (int n = 0; n < N; n++) x[n] = 0.f;
#pragma unroll
  for (int j = 0; j < LC; j++) {
    const int row = w * LC + j;
    float bb[16];
#pragma unroll
    for (int q = 0; q < 4; q++) {
      float4 bv = *(const float4*)&Bsr[row][q * 4];   // broadcast b128
      bb[q*4+0] = bv.x; bb[q*4+1] = bv.y; bb[q*4+2] = bv.z; bb[q*4+3] = bv.w;
    }
    float du = sp[j] * uu[j];
#pragma unroll
    for (int n = 0; n < N; n++) {
      float a = fexp2(sp[j] * A2[n]);
      x[n] = a * x[n] + du * bb[n];
    }
  }

  const long hb = ((long)(b * NC + c)) * N * DIM + d;   // [b][c][n][d]
#pragma unroll
  for (int n = 0; n < N; n++) h[hb + (long)n * DIM] = x[n];
  S[(b * NC + c) * DIM + d] = Ssum;
}

// ---------------- pass 2: combine (d-fastest map) ----------------
__global__ __launch_bounds__(256) void k_pass2(
    float* __restrict__ h, const float* __restrict__ S, const float* __restrict__ A)
{
  int g = blockIdx.x * 256 + threadIdx.x;   // g = (bb*16 + n)*768 + dd
  int dd = g % DIM;
  int r = g / DIM;
  int n = r & 15;
  int bb = r >> 4;
  float a2 = A[dd * N + n] * LOG2E;
  float x = 0.f;
#pragma unroll 8
  for (int cc = 0; cc < NC; cc++) {
    long idx = (((long)(bb * NC + cc)) * N + n) * DIM + dd;
    float hc = h[idx];
    float Sc = S[(bb * NC + cc) * DIM + dd];
    h[idx] = x;                     // x_init for chunk cc
    x = fexp2(Sc * a2) * x + hc;
  }
}

// ---------------- pass 3 ----------------
__global__ __launch_bounds__(256, 3) void k_pass3(
    const float* __restrict__ u, const float* __restrict__ delta,
    const float* __restrict__ A, const float* __restrict__ dbias,
    const float* __restrict__ Bg, const float* __restrict__ Cg,
    const float* __restrict__ Dv, const float* __restrict__ z,
    const float* __restrict__ xinit, float* __restrict__ out)
{
  __shared__ float ds_[64][68];   // delta slab, reused as y slab
  __shared__ float us[64][68];
  __shared__ float Bsr[64][20];
  __shared__ float Csr[64][20];

  const int bid = blockIdx.x, t = threadIdx.x;
  const int cgi = bid & 31;
  const int dgb = bid >> 5;
  const int dg = dgb % DG;
  const int b = dgb / DG;
  const int d0 = dg * 64, l0 = cgi * 64;

  {
    const int row16 = t >> 4;
    const int col4 = (t & 15) * 4;
#pragma unroll
    for (int rr = 0; rr < 4; rr++) {
      int row = row16 + rr * 16;
      long gof = ((long)(b * DIM + d0 + row)) * L + l0 + col4;
      *(float4*)&ds_[row][col4] = *(const float4*)(delta + gof);
      *(float4*)&us[row][col4]  = *(const float4*)(u + gof);
    }
    long bof = ((long)(b * N + row16)) * L + l0 + col4;
    float4 v = *(const float4*)(Bg + bof);
    Bsr[col4 + 0][row16] = v.x;
    Bsr[col4 + 1][row16] = v.y;
    Bsr[col4 + 2][row16] = v.z;
    Bsr[col4 + 3][row16] = v.w;
    float4 wv = *(const float4*)(Cg + bof);
    Csr[col4 + 0][row16] = wv.x;
    Csr[col4 + 1][row16] = wv.y;
    Csr[col4 + 2][row16] = wv.z;
    Csr[col4 + 3][row16] = wv.w;
  }

  const int w = t >> 6, lane = t & 63;
  const int c = cgi * CPB + w;
  const int d = d0 + lane;

  float A2[N];
#pragma unroll
  for (int q = 0; q < 4; q++) {
    float4 av = *(const float4*)(A + d * N + q * 4);
    A2[q*4+0] = av.x * LOG2E; A2[q*4+1] = av.y * LOG2E;
    A2[q*4+2] = av.z * LOG2E; A2[q*4+3] = av.w * LOG2E;
  }
  const float bias = dbias[d];
  const float Dd = Dv[d];

  // x_init: [b][c][n][d] -> 16 coalesced b32 loads
  const long hb = ((long)(b * NC + c)) * N * DIM + d;
  float x[N];
#pragma unroll
  for (int n = 0; n < N; n++) x[n] = xinit[hb + (long)n * DIM];

  __syncthreads();

  float sp[LC], uu[LC];
#pragma unroll
  for (int q = 0; q < 4; q++) {
    float4 dv = *(const float4*)&ds_[lane][w * LC + q * 4];
    float4 uv = *(const float4*)&us[lane][w * LC + q * 4];
    sp[q*4+0] = softplus(dv.x + bias); uu[q*4+0] = uv.x;
    sp[q*4+1] = softplus(dv.y + bias); uu[q*4+1] = uv.y;
    sp[q*4+2] = softplus(dv.z + bias); uu[q*4+2] = uv.z;
    sp[q*4+3] = softplus(dv.w + bias); uu[q*4+3] = uv.w;
  }

  __syncthreads();   // done reading ds_ as delta; will rewrite as y

  float y[LC];
#pragma unroll
  for (int j = 0; j < LC; j++) {
    const int row = w * LC + j;
    float bb[16], ccv[16];
#pragma unroll
    for (int q = 0; q < 4; q++) {
      float4 bv = *(const float4*)&Bsr[row][q * 4];   // broadcast b128
      float4 cv = *(const float4*)&Csr[row][q * 4];
      bb[q*4+0] = bv.x; bb[q*4+1] = bv.y; bb[q*4+2] = bv.z; bb[q*4+3] = bv.w;
      ccv[q*4+0] = cv.x; ccv[q*4+1] = cv.y; ccv[q*4+2] = cv.z; ccv[q*4+3] = cv.w;
    }
    float du = sp[j] * uu[j];
    float acc = 0.f;
#pragma unroll
    for (int n = 0; n < N; n++) {
      float a = fexp2(sp[j] * A2[n]);
      x[n] = a * x[n] + du * bb[n];
      acc += x[n] * ccv[n];
    }
    y[j] = acc;
  }
#pragma unroll
  for (int q = 0; q < 4; q++) {
    float4 v; v.x = y[q*4+0]; v.y = y[q*4+1]; v.z = y[q*4+2]; v.w = y[q*4+3];
    *(float4*)&ds_[lane][w * LC + q * 4] = v;
  }

  __syncthreads();

  // coalesced fused epilogue: out = (y + u*D) * silu(z)
  {
    const int row16 = t >> 4;
    const int col4 = (t & 15) * 4;
#pragma unroll
    for (int rr = 0; rr < 4; rr++) {
      int row = row16 + rr * 16;
      long gof = ((long)(b * DIM + d0 + row)) * L + l0 + col4;
      float4 zv = *(const float4*)(z + gof);
      float4 yv = *(const float4*)&ds_[row][col4];
      float4 uv = *(const float4*)&us[row][col4];
      float Dd2 = Dv[d0 + row];
      float4 ov;
      ov.x = (yv.x + uv.x * Dd2) * silu(zv.x);
      ov.y = (yv.y + uv.y * Dd2) * silu(zv.y);
      ov.z = (yv.z + uv.z * Dd2) * silu(zv.z);
      ov.w = (yv.w + uv.w * Dd2) * silu(zv.w);
      *(float4*)(out + gof) = ov;
    }
  }
}

// ---------------- fallback (ws too small) ----------------
__global__ __launch_bounds__(256) void k_simple(
    const float* __restrict__ u, const float* __restrict__ delta,
    const float* __restrict__ A, const float* __restrict__ dbias,
    const float* __restrict__ Bm, const float* __restrict__ Cm,
    const float* __restrict__ Dv, const float* __restrict__ z,
    float* __restrict__ out) {
  int t = blockIdx.x * 256 + threadIdx.x;
  int n = t % N;
  int bd = t / N;
  int d = bd % DIM;
  int b = bd / DIM;
  float A2 = A[d * N + n] * LOG2E;
  float bias = dbias[d];
  float Dd = Dv[d];
  const float* Bp = Bm + ((long)b * N + n) * L;
  const float* Cp = Cm + ((long)b * N + n) * L;
  long base = (long)bd * L;
  float x = 0.0f;
  for (int l = 0; l < L; l++) {
    float dv = delta[base + l];
    float uv = u[base + l];
    float sp = softplus(dv + bias);
    float a = fexp2(sp * A2);
    x = a * x + sp * uv * Bp[l];
    float y = x * Cp[l];
#pragma unroll
    for (int off = 8; off; off >>= 1) y += __shfl_xor(y, off, 16);
    if (n == 0) {
      float zv = z[base + l];
      out[base + l] = (y + uv * Dd) * silu(zv);
    }
  }
}

extern "C" void kernel_launch(void* const* d_in, const int* in_sizes, int n_in,
                              void* d_out, int out_size, void* d_ws, size_t ws_size,
                              hipStream_t stream) {
  const float* u     = (const float*)d_in[0];
  const float* delta = (const float*)d_in[1];
  const float* A     = (const float*)d_in[2];
  const float* Bm    = (const float*)d_in[3];
  const float* Cm    = (const float*)d_in[4];
  const float* Dv    = (const float*)d_in[5];
  const float* z     = (const float*)d_in[6];
  const float* dbias = (const float*)d_in[7];
  float* out = (float*)d_out;

  const size_t hp  = (size_t)BATCH * NC * DIM * N;  // 3.15M floats
  const size_t spn = (size_t)BATCH * NC * DIM;      // 196K floats
  const size_t need = (hp + spn) * sizeof(float);

  if (ws_size < need) {
    k_simple<<<(BATCH * DIM * N) / 256, 256, 0, stream>>>(u, delta, A, dbias, Bm, Cm, Dv, z, out);
    return;
  }

  float* h = (float*)d_ws;
  float* S = h + hp;

  k_pass1<<<NBLK, 256, 0, stream>>>(u, delta, A, dbias, Bm, h, S);
  k_pass2<<<NCOMB / 256, 256, 0, stream>>>(h, S, A);
  k_pass3<<<NBLK, 256, 0, stream>>>(u, delta, A, dbias, Bm, Cm, Dv, z, h, out);
}